// Round 2
// baseline (770.694 us; speedup 1.0000x reference)
//
#include <hip/hip_runtime.h>
#include <hip/hip_bf16.h>

#define N_TOK 100000
#define K_ITER 16

typedef __attribute__((ext_vector_type(8))) short short8;
typedef __attribute__((ext_vector_type(4))) float floatx4;

static __device__ __forceinline__ unsigned short f2bf(float x) {
  unsigned u = __float_as_uint(x);
  u += 0x7FFFu + ((u >> 16) & 1u);   // RNE
  return (unsigned short)(u >> 16);
}

// ---------------- kernel 1: sims[b,n] = -dot(q,keys)/sqrt(128); fused sum(exp(sims)) per b
__global__ __launch_bounds__(256) void k_sims(const float* __restrict__ q,
                                              const float* __restrict__ keys,
                                              float* __restrict__ sims,
                                              float* __restrict__ scal) {
  __shared__ float qs[128];
  __shared__ float red[4];
  const int b = blockIdx.y;
  const int tid = threadIdx.x;
  if (tid < 128) qs[tid] = q[b * 128 + tid];
  __syncthreads();
  const int n0 = blockIdx.x * 1024 + tid * 4;
  float part = 0.f;
  if (n0 < N_TOK) {
    const float* kb = keys + (size_t)b * 128 * N_TOK + n0;
    float ax = 0.f, ay = 0.f, az = 0.f, aw = 0.f;
#pragma unroll 8
    for (int d = 0; d < 128; ++d) {
      float4 kv = *(const float4*)(kb + (size_t)d * N_TOK);
      float qd = qs[d];
      ax = fmaf(qd, kv.x, ax); ay = fmaf(qd, kv.y, ay);
      az = fmaf(qd, kv.z, az); aw = fmaf(qd, kv.w, aw);
    }
    const float sc = -0.08838834764831843f;  // -1/sqrt(128)
    float4 s4; s4.x = ax * sc; s4.y = ay * sc; s4.z = az * sc; s4.w = aw * sc;
    *(float4*)(sims + (size_t)b * N_TOK + n0) = s4;
    part = __expf(s4.x) + __expf(s4.y) + __expf(s4.z) + __expf(s4.w);
  }
#pragma unroll
  for (int off = 32; off > 0; off >>= 1) part += __shfl_down(part, off);
  if ((tid & 63) == 0) red[tid >> 6] = part;
  __syncthreads();
  if (tid == 0) atomicAdd(&scal[b * 32], red[0] + red[1] + red[2] + red[3]);
}

// ---------------- kernel 2: moments M1,M2,M3 of E0 = exp(10*alpha0), alpha0 = exp(s)/S0
__global__ __launch_bounds__(256) void k_mom(const float* __restrict__ sims,
                                             float* __restrict__ scal) {
  __shared__ float red[3][4];
  const int b = blockIdx.y;
  const int tid = threadIdx.x;
  const float r0 = 1.f / scal[b * 32];
  const int n0 = blockIdx.x * 1024 + tid * 4;
  float m1 = 0.f, m2 = 0.f, m3 = 0.f;
  if (n0 < N_TOK) {
    float4 s4 = *(const float4*)(sims + (size_t)b * N_TOK + n0);
    float e;
    e = __expf(10.f * __expf(s4.x) * r0); m1 += e; m2 += e * e; m3 += e * e * e;
    e = __expf(10.f * __expf(s4.y) * r0); m1 += e; m2 += e * e; m3 += e * e * e;
    e = __expf(10.f * __expf(s4.z) * r0); m1 += e; m2 += e * e; m3 += e * e * e;
    e = __expf(10.f * __expf(s4.w) * r0); m1 += e; m2 += e * e; m3 += e * e * e;
  }
#pragma unroll
  for (int off = 32; off > 0; off >>= 1) {
    m1 += __shfl_down(m1, off); m2 += __shfl_down(m2, off); m3 += __shfl_down(m3, off);
  }
  if ((tid & 63) == 0) { int w = tid >> 6; red[0][w] = m1; red[1][w] = m2; red[2][w] = m3; }
  __syncthreads();
  if (tid == 0) {
    atomicAdd(&scal[b * 32 + 1], red[0][0] + red[0][1] + red[0][2] + red[0][3]);
    atomicAdd(&scal[b * 32 + 2], red[1][0] + red[1][1] + red[1][2] + red[1][3]);
    atomicAdd(&scal[b * 32 + 3], red[2][0] + red[2][1] + red[2][2] + red[2][3]);
  }
}

// ---------------- kernel 3: recompute w-chain per n, MFMA einsum out[k,f] += w_k[n]*V[f,n]
__global__ __launch_bounds__(256) void k_main(const float* __restrict__ sims,
                                              const float* __restrict__ values,
                                              const float* __restrict__ scal,
                                              float* __restrict__ outacc) {
  __shared__ unsigned short Vlds[128][136];  // bf16 bits, padded stride
  __shared__ unsigned short Wlds[16][136];
  const int b = blockIdx.y;
  const int tid = threadIdx.x;
  // scalar recurrence: S_{k+1} = S - 10 r M2 + 45 r^2 M3 ; M2 -= 20 r M3 (r = 1/S)
  const float r0 = 1.f / scal[b * 32 + 0];
  float S  = scal[b * 32 + 1];
  float m2 = scal[b * 32 + 2];
  float m3 = scal[b * 32 + 3];
  float R[K_ITER];
#pragma unroll
  for (int k = 0; k < K_ITER; ++k) {
    float r = 1.f / S;
    R[k] = r;
    S  = S - 10.f * r * m2 + 45.f * r * r * m3;
    m2 = m2 - 20.f * r * m3;
  }
  const float* vb = values + (size_t)b * 128 * N_TOK;
  const int lane = tid & 63, wv = tid >> 6;
  const int col = lane & 15, quad = lane >> 4;
  floatx4 acc0 = {0.f, 0.f, 0.f, 0.f};
  floatx4 acc1 = {0.f, 0.f, 0.f, 0.f};

  for (int c = blockIdx.x; c < 782; c += 112) {
    const int nb = c * 128;
    __syncthreads();  // previous chunk's MFMA reads done
    // stage V chunk (128 f x 128 n) as bf16
#pragma unroll
    for (int i = 0; i < 16; ++i) {
      int L = tid + i * 256;
      int f = L >> 5, jj = L & 31;
      int n = nb + jj * 4;
      uint2 pk; pk.x = 0u; pk.y = 0u;
      if (n < N_TOK) {
        float4 v = *(const float4*)(vb + (size_t)f * N_TOK + n);
        pk.x = (unsigned)f2bf(v.x) | ((unsigned)f2bf(v.y) << 16);
        pk.y = (unsigned)f2bf(v.z) | ((unsigned)f2bf(v.w) << 16);
      }
      *(uint2*)&Vlds[f][jj * 4] = pk;
    }
    // recompute w-chain for this chunk's 128 n
    if (tid < 128) {
      int n = nb + tid;
      bool valid = n < N_TOK;
      float E = 0.f;
      if (valid) {
        float s0 = sims[(size_t)b * N_TOK + n];
        E = __expf(10.f * __expf(s0) * r0);
      }
#pragma unroll
      for (int k = 0; k < K_ITER; ++k) {
        unsigned short wb = 0;
        if (valid) {
          float w = E * R[k];
          wb = f2bf(w);
          E *= fmaf(w, fmaf(45.f, w, -10.f), 1.f);  // E *= (1-w)^10 to O(w^3)
        }
        Wlds[k][tid] = wb;
      }
    }
    __syncthreads();
    // MFMA: D[16 kout x 16 f] += A[16 kout x 32 n] * B[32 n x 16 f]
#pragma unroll
    for (int s = 0; s < 4; ++s) {
      int no = s * 32 + quad * 8;
      short8 af = *(const short8*)&Wlds[col][no];
      short8 b0 = *(const short8*)&Vlds[wv * 32 + col][no];
      short8 b1 = *(const short8*)&Vlds[wv * 32 + 16 + col][no];
      acc0 = __builtin_amdgcn_mfma_f32_16x16x32_bf16(af, b0, acc0, 0, 0, 0);
      acc1 = __builtin_amdgcn_mfma_f32_16x16x32_bf16(af, b1, acc1, 0, 0, 0);
    }
  }
  // D layout: col = lane&15 (f), row = quad*4 + r (k_out)
#pragma unroll
  for (int r = 0; r < 4; ++r) {
    int ko = quad * 4 + r;
    atomicAdd(&outacc[((b << 4) + ko) * 128 + wv * 32 + col], acc0[r]);
    atomicAdd(&outacc[((b << 4) + ko) * 128 + wv * 32 + 16 + col], acc1[r]);
  }
}

// ---------------- kernel 4: f32 accumulator -> f32 output (overwrite, d_out is poisoned)
__global__ __launch_bounds__(256) void k_out(const float* __restrict__ outacc,
                                             float* __restrict__ out) {
  int i = blockIdx.x * 256 + threadIdx.x;
  if (i < 16384) out[i] = outacc[i];
}

extern "C" void kernel_launch(void* const* d_in, const int* in_sizes, int n_in,
                              void* d_out, int out_size, void* d_ws, size_t ws_size,
                              hipStream_t stream) {
  const float* q      = (const float*)d_in[0];
  const float* keys   = (const float*)d_in[1];
  const float* values = (const float*)d_in[2];
  float* outacc = (float*)d_ws;          // 16384 f32 partial-out accumulator
  float* scal   = outacc + 16384;        // 8 batches x 32 scalar slots
  float* sims   = scal + 256;            // 800000 f32
  hipMemsetAsync(d_ws, 0, (16384 + 256) * sizeof(float), stream);
  dim3 g1(98, 8);
  k_sims<<<g1, 256, 0, stream>>>(q, keys, sims, scal);
  k_mom<<<g1, 256, 0, stream>>>(sims, scal);
  dim3 g3(112, 8);
  k_main<<<g3, 256, 0, stream>>>(sims, values, scal, outacc);
  k_out<<<64, 256, 0, stream>>>(outacc, (float*)d_out);
}